// Round 15
// baseline (941.207 us; speedup 1.0000x reference)
//
#include <hip/hip_runtime.h>
#include <hip/hip_bf16.h>
#include <hip/hip_cooperative_groups.h>
#include <math.h>

namespace cg = cooperative_groups;

#define N_NODES 20000
#define N_EDGES 640000
#define ET_EDGES (N_EDGES + N_NODES)   // with self-loops
#define G_GRAPHS 64
#define NEG_SLOPE 0.2f

#define NBC 1024                       // cooperative grid blocks
#define CHC ((N_NODES + NBC - 1) / NBC)  // 20 nodes per block in scan

typedef __attribute__((ext_vector_type(8))) short s8v;   // 8 bf16 (4 VGPR)
typedef __attribute__((ext_vector_type(4))) float f4v;   // 4 fp32 acc

// fp32 -> bf16 (RNE) and back
__device__ __forceinline__ unsigned short bf_hi(float f) {
    union { float f; unsigned int u; } c; c.f = f;
    unsigned int r = (c.u + 0x7fffu + ((c.u >> 16) & 1u)) >> 16;
    return (unsigned short)r;
}
__device__ __forceinline__ float bf_f(unsigned short h) {
    union { unsigned int u; float f; } c; c.u = ((unsigned int)h) << 16;
    return c.f;
}

// ---------------- cooperative front-end: prep + CSR build in ONE dispatch ----
// P1 zero+splits -> sync -> P2 histogram+gstart -> sync -> P3 3-level scan
// -> sync -> P4 fill. Replaces 4 dispatches (R14: prep_split, hist_dst,
// scan_rowptr, fill_csr) -> 3 fewer launch boundaries, scan fully parallel.
// Grid 1024x256: 4 blocks/CU, ~10KB LDS -> co-residency guaranteed.

__global__ void __launch_bounds__(256) build_all(
        const float* __restrict__ x,
        const float* __restrict__ W1, const float* __restrict__ W2,
        const float* __restrict__ W3,
        const int* __restrict__ ei, const int* __restrict__ batch,
        unsigned short* __restrict__ xh, unsigned short* __restrict__ xl,
        unsigned short* __restrict__ w1h, unsigned short* __restrict__ w1l,
        unsigned short* __restrict__ w2h, unsigned short* __restrict__ w2l,
        unsigned short* __restrict__ w3h, unsigned short* __restrict__ w3l,
        int* __restrict__ cntcur,          // cnt followed by cur (contiguous)
        float* __restrict__ gout, float* __restrict__ a3z,
        int* __restrict__ row_ptr, int* __restrict__ col,
        int* __restrict__ gstart, int* __restrict__ bsum) {
    cg::grid_group grid = cg::this_grid();
    __shared__ int l2[NBC];            // block0 scan staging (4KB)
    __shared__ int ps[256];
    int tid = blockIdx.x * blockDim.x + threadIdx.x;
    int nth = gridDim.x * blockDim.x;  // 262144
    int* cnt = cntcur;
    int* cur = cntcur + N_NODES;

    // ---- P1: splits + zeroing (793120 work items) ----
    for (int idx = tid; idx < 793120; idx += nth) {
        int q = idx;
        if (q < 640000) {                   // x f32 -> hi/lo bf16, vec4
            int i = q * 4;
            float4 v = *(const float4*)&x[i];
            ushort4 h, l;
            h.x = bf_hi(v.x); l.x = bf_hi(v.x - bf_f(h.x));
            h.y = bf_hi(v.y); l.y = bf_hi(v.y - bf_f(h.y));
            h.z = bf_hi(v.z); l.z = bf_hi(v.z - bf_f(h.z));
            h.w = bf_hi(v.w); l.w = bf_hi(v.w - bf_f(h.w));
            *(ushort4*)&xh[i] = h;
            *(ushort4*)&xl[i] = l;
            continue;
        }
        q -= 640000;
        if (q < 32768) {                    // W1 [128][256] -> [256][128]
            int k = q / 256, n = q % 256;
            float v = W1[q];
            unsigned short h = bf_hi(v);
            w1h[n * 128 + k] = h;
            w1l[n * 128 + k] = bf_hi(v - bf_f(h));
            continue;
        }
        q -= 32768;
        if (q < 65536) {                    // W2 [256][256] -> [256][256]
            int k = q / 256, n = q % 256;
            float v = W2[q];
            unsigned short h = bf_hi(v);
            w2h[n * 256 + k] = h;
            w2l[n * 256 + k] = bf_hi(v - bf_f(h));
            continue;
        }
        q -= 65536;
        if (q < 32768) {                    // W3 [256][128] -> [128][256]
            int k = q / 128, n = q % 128;
            float v = W3[q];
            unsigned short h = bf_hi(v);
            w3h[n * 256 + k] = h;
            w3l[n * 256 + k] = bf_hi(v - bf_f(h));
            continue;
        }
        q -= 32768;
        if (q < 10000) {                    // zero cnt+cur
            *(int4*)&cntcur[q * 4] = make_int4(0, 0, 0, 0);
            continue;
        }
        q -= 10000;
        if (q < 2048) {                     // zero gout
            *(float4*)&gout[q * 4] = make_float4(0.f, 0.f, 0.f, 0.f);
            continue;
        }
        q -= 2048;
        // zero asv3+adv3 (40000 f32)
        *(float4*)&a3z[q * 4] = make_float4(0.f, 0.f, 0.f, 0.f);
    }
    grid.sync();

    // ---- P2: dst histogram + per-graph bounds ----
    for (int j = tid; j < ET_EDGES; j += nth) {
        int d = (j < N_EDGES) ? ei[N_EDGES + j] : (j - N_EDGES);
        atomicAdd(&cnt[d], 1);
    }
    if (tid <= G_GRAPHS) {
        int g = tid;
        int lo = 0, hi = N_NODES;
        while (lo < hi) {                   // first i with batch[i] >= g
            int mid = (lo + hi) >> 1;
            if (batch[mid] < g) lo = mid + 1; else hi = mid;
        }
        gstart[g] = lo;
    }
    grid.sync();

    // ---- P3a: per-block partial sums of cnt chunks ----
    {
        int t = threadIdx.x, b = blockIdx.x;
        int s = 0;
        int base = b * CHC;
        for (int i = t; i < CHC; i += 256) {
            int idx = base + i;
            if (idx < N_NODES) s += cnt[idx];
        }
        ps[t] = s;
        __syncthreads();
        for (int o = 128; o; o >>= 1) {
            if (t < o) ps[t] += ps[t + o];
            __syncthreads();
        }
        if (t == 0) bsum[b] = ps[0];
    }
    grid.sync();

    // ---- P3b: block 0 scans the NBC block sums (exclusive) ----
    if (blockIdx.x == 0) {
        int t = threadIdx.x;
        for (int i = t; i < NBC; i += 256) l2[i] = bsum[i];
        __syncthreads();
        int s = 0;
        #pragma unroll
        for (int k = 0; k < NBC / 256; ++k) s += l2[t * (NBC / 256) + k];
        ps[t] = s;
        __syncthreads();
        for (int o = 1; o < 256; o <<= 1) {
            int v = (t >= o) ? ps[t - o] : 0;
            __syncthreads();
            ps[t] += v;
            __syncthreads();
        }
        int run = (t == 0) ? 0 : ps[t - 1];
        #pragma unroll
        for (int k = 0; k < NBC / 256; ++k) {
            int i = t * (NBC / 256) + k;
            int c = l2[i]; l2[i] = run; run += c;
        }
        __syncthreads();
        for (int i = t; i < NBC; i += 256) bsum[i] = l2[i];
    }
    grid.sync();

    // ---- P3c: per-block exclusive prefix into row_ptr ----
    if (threadIdx.x == 0) {
        int b = blockIdx.x;
        int run = bsum[b];
        int base = b * CHC;
        for (int i = 0; i < CHC; ++i) {
            int idx = base + i;
            if (idx < N_NODES) { row_ptr[idx] = run; run += cnt[idx]; }
        }
        if (b == NBC - 1) row_ptr[N_NODES] = run;
    }
    grid.sync();

    // ---- P4: fill CSR ----
    for (int j = tid; j < ET_EDGES; j += nth) {
        int s, d;
        if (j < N_EDGES) { s = ei[j]; d = ei[N_EDGES + j]; }
        else             { s = d = j - N_EDGES; }
        int pos = row_ptr[d] + atomicAdd(&cur[d], 1);
        col[pos] = s;
    }
}

// ---------------- split-bf16 MFMA GEMM, 128x128 tile + fused alpha ----------
// C = Ah*Bh + Ah*Bl + Al*Bh (lo*lo ~2^-18 rel, dropped). fp32 accumulate.
// Tile 128x128, 4 waves of 64x64 (48 MFMA per 32-K step). Register prefetch
// of the next K-tile hides HBM latency under the MFMA block (R14, -15us).
// Alpha epilogue: CPH=64 -> wave covers a full head, direct store; CPH=128
// (layer 3) -> half head, atomicAdd into pre-zeroed bufs (R10 fix).

#define LDT 40

template <int CPH>
__global__ __launch_bounds__(256) void gemm_split(
        const unsigned short* __restrict__ Ah, const unsigned short* __restrict__ Al,
        const unsigned short* __restrict__ Bh, const unsigned short* __restrict__ Bl,
        float* __restrict__ C, int M, int Nc, int K,
        const float* __restrict__ a_src, const float* __restrict__ a_dst,
        float* __restrict__ asT, float* __restrict__ adT) {
    __shared__ unsigned short lAh[128 * LDT];
    __shared__ unsigned short lAl[128 * LDT];
    __shared__ unsigned short lBh[128 * LDT];
    __shared__ unsigned short lBl[128 * LDT];
    int bm = blockIdx.x * 128, bn = blockIdx.y * 128;
    int t = threadIdx.x, w = t >> 6, lane = t & 63;
    int wm = (w >> 1) * 64, wn = (w & 1) * 64;

    f4v acc[4][4] = {};

    int sr = t >> 1, sk = (t & 1) << 4;
    int ar = bm + sr; if (ar >= M) ar = M - 1;
    const unsigned short* pAh = Ah + (size_t)ar * K + sk;
    const unsigned short* pAl = Al + (size_t)ar * K + sk;
    const unsigned short* pBh = Bh + (size_t)(bn + sr) * K + sk;
    const unsigned short* pBl = Bl + (size_t)(bn + sr) * K + sk;

    int fr = lane & 15, fk = (lane >> 4) << 3;

    // preload K-tile 0
    uint4 vh0 = *(const uint4*)(pAh + 0);
    uint4 vh1 = *(const uint4*)(pAh + 8);
    uint4 vl0 = *(const uint4*)(pAl + 0);
    uint4 vl1 = *(const uint4*)(pAl + 8);
    uint4 wh0 = *(const uint4*)(pBh + 0);
    uint4 wh1 = *(const uint4*)(pBh + 8);
    uint4 wl0 = *(const uint4*)(pBl + 0);
    uint4 wl1 = *(const uint4*)(pBl + 8);

    for (int k0 = 0; k0 < K; k0 += 32) {
        __syncthreads();
        *(uint4*)&lAh[sr * LDT + sk]     = vh0;
        *(uint4*)&lAh[sr * LDT + sk + 8] = vh1;
        *(uint4*)&lAl[sr * LDT + sk]     = vl0;
        *(uint4*)&lAl[sr * LDT + sk + 8] = vl1;
        *(uint4*)&lBh[sr * LDT + sk]     = wh0;
        *(uint4*)&lBh[sr * LDT + sk + 8] = wh1;
        *(uint4*)&lBl[sr * LDT + sk]     = wl0;
        *(uint4*)&lBl[sr * LDT + sk + 8] = wl1;
        __syncthreads();

        int kn = k0 + 32;
        if (kn < K) {                      // prefetch next tile (hides HBM)
            vh0 = *(const uint4*)(pAh + kn);
            vh1 = *(const uint4*)(pAh + kn + 8);
            vl0 = *(const uint4*)(pAl + kn);
            vl1 = *(const uint4*)(pAl + kn + 8);
            wh0 = *(const uint4*)(pBh + kn);
            wh1 = *(const uint4*)(pBh + kn + 8);
            wl0 = *(const uint4*)(pBl + kn);
            wl1 = *(const uint4*)(pBl + kn + 8);
        }

        s8v a_h[4], a_l[4], b_h[4], b_l[4];
        #pragma unroll
        for (int mi = 0; mi < 4; ++mi) {
            a_h[mi] = *(const s8v*)&lAh[(wm + mi * 16 + fr) * LDT + fk];
            a_l[mi] = *(const s8v*)&lAl[(wm + mi * 16 + fr) * LDT + fk];
        }
        #pragma unroll
        for (int nj = 0; nj < 4; ++nj) {
            b_h[nj] = *(const s8v*)&lBh[(wn + nj * 16 + fr) * LDT + fk];
            b_l[nj] = *(const s8v*)&lBl[(wn + nj * 16 + fr) * LDT + fk];
        }
        #pragma unroll
        for (int mi = 0; mi < 4; ++mi)
            #pragma unroll
            for (int nj = 0; nj < 4; ++nj) {
                acc[mi][nj] = __builtin_amdgcn_mfma_f32_16x16x32_bf16(
                    a_h[mi], b_h[nj], acc[mi][nj], 0, 0, 0);
                acc[mi][nj] = __builtin_amdgcn_mfma_f32_16x16x32_bf16(
                    a_h[mi], b_l[nj], acc[mi][nj], 0, 0, 0);
                acc[mi][nj] = __builtin_amdgcn_mfma_f32_16x16x32_bf16(
                    a_l[mi], b_h[nj], acc[mi][nj], 0, 0, 0);
            }
    }

    // C/D layout: col = lane&15, row = (lane>>4)*4 + q  [verified gfx950]
    #pragma unroll
    for (int mi = 0; mi < 4; ++mi)
        #pragma unroll
        for (int nj = 0; nj < 4; ++nj) {
            int row0 = bm + wm + mi * 16 + (lane >> 4) * 4;
            int colc = bn + wn + nj * 16 + (lane & 15);
            #pragma unroll
            for (int q = 0; q < 4; ++q) {
                int r = row0 + q;
                if (r < M) C[(size_t)r * Nc + colc] = acc[mi][nj][q];
            }
        }

    // ---- fused alpha epilogue ----
    float av_s[4], av_d[4];
    #pragma unroll
    for (int nj = 0; nj < 4; ++nj) {
        int aidx = bn + wn + nj * 16 + fr;
        av_s[nj] = a_src[aidx];
        av_d[nj] = a_dst[aidx];
    }
    int head = (bn + wn) / CPH;
    #pragma unroll
    for (int mi = 0; mi < 4; ++mi) {
        #pragma unroll
        for (int q = 0; q < 4; ++q) {
            float ps = acc[mi][0][q] * av_s[0] + acc[mi][1][q] * av_s[1]
                     + acc[mi][2][q] * av_s[2] + acc[mi][3][q] * av_s[3];
            float pd = acc[mi][0][q] * av_d[0] + acc[mi][1][q] * av_d[1]
                     + acc[mi][2][q] * av_d[2] + acc[mi][3][q] * av_d[3];
            #pragma unroll
            for (int o = 1; o < 16; o <<= 1) {
                ps += __shfl_xor(ps, o);
                pd += __shfl_xor(pd, o);
            }
            if (fr == 0) {
                int r = bm + wm + mi * 16 + (lane >> 4) * 4 + q;
                if (r < M) {
                    if (CPH == 64) {          // wave == full head: direct store
                        asT[(size_t)head * M + r] = ps;
                        adT[(size_t)head * M + r] = pd;
                    } else {                  // half head: atomic combine
                        atomicAdd(&asT[r], ps);
                        atomicAdd(&adT[r], pd);
                    }
                }
            }
        }
    }
}

// ---------------- channel-sliced softmax-aggregate (R10-measured optimum) ---
// NSLICE=4, fused softmax, fp32 table, GATHER4, VGPR 28 — every probed
// perturbation (NSLICE 1/8, unroll 8, precomputed pex, fp16 table) lost.

template <int NSLICE, int SCH, int F, int HEADS, bool DO_ELU, bool SPLIT>
__global__ __launch_bounds__(256) void gat_aggregate_sliced(
        const float* __restrict__ h,      // [N, F]
        const float* __restrict__ asT,    // [HEADS][N]
        const float* __restrict__ adT,    // [HEADS][N]
        const int* __restrict__ row_ptr,
        const int* __restrict__ col,
        const float* __restrict__ bias,   // [F]
        float* __restrict__ out,          // [N, F]   (SPLIT=false)
        unsigned short* __restrict__ oh,  // [N, F]   (SPLIT=true)
        unsigned short* __restrict__ ol) {
    constexpr int CL = SCH / 4;           // lanes per edge (16 or 8)
    constexpr int E  = 64 / CL;           // parallel edges (4 or 8)
    constexpr int CPH = F / HEADS;        // channels per head
    __shared__ int   s_off[4][64];
    __shared__ float s_p[4][64];
    int slice = blockIdx.x & (NSLICE - 1);
    int ng = blockIdx.x >> 2;             // NSLICE == 4
    int wid = threadIdx.x >> 6, lane = threadIdx.x & 63;
    int v = ng * 4 + wid;
    if (v >= N_NODES) return;
    int head = (slice * SCH) / CPH;       // layers 1/2: slice == head; layer 3: 0
    int eg = lane / CL, cl = lane % CL;
    int r0 = row_ptr[v], r1 = row_ptr[v + 1];
    float ad = adT[head * N_NODES + v];
    const float* asrc = asT + head * N_NODES;
    float acc[4] = {};
    float lsum = 0.f;
    const char* hb = (const char*)(h + slice * SCH + cl * 4);

#define GATHER4(gg)                                                        \
    {                                                                      \
        int k0 = ((gg) + 0) * E + eg;                                      \
        int k1 = ((gg) + 1) * E + eg;                                      \
        int k2 = ((gg) + 2) * E + eg;                                      \
        int k3 = ((gg) + 3) * E + eg;                                      \
        float p0 = s_p[wid][k0]; int o0 = s_off[wid][k0];                  \
        float p1 = s_p[wid][k1]; int o1 = s_off[wid][k1];                  \
        float p2 = s_p[wid][k2]; int o2 = s_off[wid][k2];                  \
        float p3 = s_p[wid][k3]; int o3 = s_off[wid][k3];                  \
        float4 h0 = *(const float4*)(hb + o0);                             \
        float4 h1 = *(const float4*)(hb + o1);                             \
        float4 h2 = *(const float4*)(hb + o2);                             \
        float4 h3 = *(const float4*)(hb + o3);                             \
        acc[0] = fmaf(p0, h0.x, acc[0]);                                   \
        acc[1] = fmaf(p0, h0.y, acc[1]);                                   \
        acc[2] = fmaf(p0, h0.z, acc[2]);                                   \
        acc[3] = fmaf(p0, h0.w, acc[3]);                                   \
        acc[0] = fmaf(p1, h1.x, acc[0]);                                   \
        acc[1] = fmaf(p1, h1.y, acc[1]);                                   \
        acc[2] = fmaf(p1, h1.z, acc[2]);                                   \
        acc[3] = fmaf(p1, h1.w, acc[3]);                                   \
        acc[0] = fmaf(p2, h2.x, acc[0]);                                   \
        acc[1] = fmaf(p2, h2.y, acc[1]);                                   \
        acc[2] = fmaf(p2, h2.z, acc[2]);                                   \
        acc[3] = fmaf(p2, h2.w, acc[3]);                                   \
        acc[0] = fmaf(p3, h3.x, acc[0]);                                   \
        acc[1] = fmaf(p3, h3.y, acc[1]);                                   \
        acc[2] = fmaf(p3, h3.z, acc[2]);                                   \
        acc[3] = fmaf(p3, h3.w, acc[3]);                                   \
    }

    for (int base = r0; base < r1; base += 64) {
        int j = base + lane;
        bool valid = j < r1;
        int s = col[valid ? j : r0];
        float e = asrc[s] + ad;
        e = (e > 0.f) ? e : NEG_SLOPE * e;
        float p = valid ? __expf(e) : 0.f;
        lsum += p;
        s_p[wid][lane] = p;
        s_off[wid][lane] = s * (F * 4);   // byte offset of row s

        int nk = min(64, r1 - base);
        int nkg = (nk + E - 1) / E;       // <= 64/E
        int g = 0;
        for (; g + 4 <= nkg; g += 4) GATHER4(g);
        if (g < nkg) GATHER4(g);          // ragged tail: extra groups have p==0
    }
#undef GATHER4

    // full-wave softmax denominator
    #pragma unroll
    for (int o = 32; o; o >>= 1) lsum += __shfl_xor(lsum, o);
    // reduce acc across edge groups (lanes differing in bits >= log2(CL))
    #pragma unroll
    for (int c = 0; c < 4; ++c) {
        #pragma unroll
        for (int o = CL; o < 64; o <<= 1) acc[c] += __shfl_xor(acc[c], o);
    }
    if (eg == 0) {
        float inv = 1.f / (lsum + 1e-16f);
        int ch0 = slice * SCH + cl * 4;
        float o4[4];
        #pragma unroll
        for (int c = 0; c < 4; ++c) {
            float o = acc[c] * inv + bias[ch0 + c];
            if (DO_ELU) o = (o > 0.f) ? o : expm1f(o);
            o4[c] = o;
        }
        if constexpr (SPLIT) {
            ushort4 hv4, lv4;
            hv4.x = bf_hi(o4[0]); lv4.x = bf_hi(o4[0] - bf_f(hv4.x));
            hv4.y = bf_hi(o4[1]); lv4.y = bf_hi(o4[1] - bf_f(hv4.y));
            hv4.z = bf_hi(o4[2]); lv4.z = bf_hi(o4[2] - bf_f(hv4.z));
            hv4.w = bf_hi(o4[3]); lv4.w = bf_hi(o4[3] - bf_f(hv4.w));
            *(ushort4*)&oh[(size_t)v * F + ch0] = hv4;
            *(ushort4*)&ol[(size_t)v * F + ch0] = lv4;
        } else {
            *(float4*)&out[(size_t)v * F + ch0] =
                make_float4(o4[0], o4[1], o4[2], o4[3]);
        }
    }
}

// ---------------- global mean pool: 4-way row-split + atomic combine --------

__global__ void pool_mean4(const float* __restrict__ hout, const int* __restrict__ gstart,
                           float* __restrict__ gout) {
    int g = blockIdx.x;       // 64
    int q = blockIdx.y;       // 4 row-quarters
    int c = threadIdx.x;      // 128 channels
    int off = gstart[g], end = gstart[g + 1];
    float inv = 1.f / fmaxf((float)(end - off), 1.0f);
    float s = 0.f;
    for (int i = off + q; i < end; i += 4) s += hout[(size_t)i * 128 + c];
    atomicAdd(&gout[g * 128 + c], s * inv);
}

// ---------------- launch ----------------

static inline size_t align_up(size_t x, size_t a) { return (x + a - 1) & ~(a - 1); }

extern "C" void kernel_launch(void* const* d_in, const int* in_sizes, int n_in,
                              void* d_out, int out_size, void* d_ws, size_t ws_size,
                              hipStream_t stream) {
    const float* x   = (const float*)d_in[0];
    const int*   ei  = (const int*)d_in[1];
    const int*   bat = (const int*)d_in[2];
    const float* W1  = (const float*)d_in[3];
    const float* as1 = (const float*)d_in[4];
    const float* ad1 = (const float*)d_in[5];
    const float* b1  = (const float*)d_in[6];
    const float* W2  = (const float*)d_in[7];
    const float* as2 = (const float*)d_in[8];
    const float* ad2 = (const float*)d_in[9];
    const float* b2  = (const float*)d_in[10];
    const float* W3  = (const float*)d_in[11];
    const float* as3 = (const float*)d_in[12];
    const float* ad3 = (const float*)d_in[13];
    const float* b3  = (const float*)d_in[14];

    float* gout = (float*)d_out;                     // [G,128]
    float* hout = (float*)d_out + G_GRAPHS * 128;    // [N,128]

    char* w = (char*)d_ws;
    size_t o = 0;
    float* bufA = (float*)(w + o);           o = align_up(o + (size_t)N_NODES * 256 * 4, 256);
    unsigned short* Bh = (unsigned short*)(w + o); o = align_up(o + (size_t)N_NODES * 256 * 2, 256);
    unsigned short* Bl = (unsigned short*)(w + o); o = align_up(o + (size_t)N_NODES * 256 * 2, 256);
    unsigned short* xh = (unsigned short*)(w + o); o = align_up(o + (size_t)N_NODES * 128 * 2, 256);
    unsigned short* xl = (unsigned short*)(w + o); o = align_up(o + (size_t)N_NODES * 128 * 2, 256);
    unsigned short* Wt1h = (unsigned short*)(w + o); o = align_up(o + (size_t)256 * 128 * 2, 256);
    unsigned short* Wt1l = (unsigned short*)(w + o); o = align_up(o + (size_t)256 * 128 * 2, 256);
    unsigned short* Wt2h = (unsigned short*)(w + o); o = align_up(o + (size_t)256 * 256 * 2, 256);
    unsigned short* Wt2l = (unsigned short*)(w + o); o = align_up(o + (size_t)256 * 256 * 2, 256);
    unsigned short* Wt3h = (unsigned short*)(w + o); o = align_up(o + (size_t)128 * 256 * 2, 256);
    unsigned short* Wt3l = (unsigned short*)(w + o); o = align_up(o + (size_t)128 * 256 * 2, 256);
    // per-layer alpha buffers (only asv3/adv3 need pre-zeroing)
    float* alpha = (float*)(w + o);
    float* asv1 = alpha;                  // [4][N]
    float* adv1 = alpha + 4 * N_NODES;    // [4][N]
    float* asv2 = alpha + 8 * N_NODES;    // [4][N]
    float* adv2 = alpha + 12 * N_NODES;   // [4][N]
    float* asv3 = alpha + 16 * N_NODES;   // [N]
    float* adv3 = alpha + 17 * N_NODES;   // [N]
    o = align_up(o + (size_t)18 * N_NODES * 4, 256);
    int* row_ptr = (int*)(w + o);  o = align_up(o + (size_t)(N_NODES + 1) * 4, 256);
    int* col     = (int*)(w + o);  o = align_up(o + (size_t)ET_EDGES * 4, 256);
    int* cnt     = (int*)(w + o);  o += (size_t)N_NODES * 4;        // cnt+cur contiguous
    int* cur     = (int*)(w + o);  o = align_up(o + (size_t)N_NODES * 4, 256);
    int* gstart  = (int*)(w + o);  o = align_up(o + (size_t)(G_GRAPHS + 1) * 4, 256);
    int* bsum    = (int*)(w + o);  o = align_up(o + (size_t)NBC * 4, 256);

    // ---- cooperative front-end: prep + CSR in one dispatch ----
    {
        void* args[] = {
            (void*)&x, (void*)&W1, (void*)&W2, (void*)&W3,
            (void*)&ei, (void*)&bat,
            (void*)&xh, (void*)&xl,
            (void*)&Wt1h, (void*)&Wt1l, (void*)&Wt2h, (void*)&Wt2l,
            (void*)&Wt3h, (void*)&Wt3l,
            (void*)&cnt, (void*)&gout, (void*)&asv3,
            (void*)&row_ptr, (void*)&col, (void*)&gstart, (void*)&bsum,
        };
        hipLaunchCooperativeKernel((const void*)build_all, dim3(NBC), dim3(256),
                                   args, 0, stream);
    }

    int gm = (N_NODES + 127) / 128;   // 157
    int nb = (N_NODES + 3) / 4;       // 4 nodes per block
    int nbs = nb * 4;                 // x4 channel slices

    // ---- layer 1: 128 -> 4x64 (alpha fused into GEMM epilogue) ----
    gemm_split<64><<<dim3(gm, 2), 256, 0, stream>>>(
        xh, xl, Wt1h, Wt1l, bufA, N_NODES, 256, 128, as1, ad1, asv1, adv1);
    gat_aggregate_sliced<4, 64, 256, 4, true, true><<<nbs, 256, 0, stream>>>(
        bufA, asv1, adv1, row_ptr, col, b1, nullptr, Bh, Bl);

    // ---- layer 2: 256 -> 4x64 ----
    gemm_split<64><<<dim3(gm, 2), 256, 0, stream>>>(
        Bh, Bl, Wt2h, Wt2l, bufA, N_NODES, 256, 256, as2, ad2, asv2, adv2);
    gat_aggregate_sliced<4, 64, 256, 4, true, true><<<nbs, 256, 0, stream>>>(
        bufA, asv2, adv2, row_ptr, col, b2, nullptr, Bh, Bl);

    // ---- layer 3: 256 -> 128 (1 head; half-head waves -> atomics) ----
    gemm_split<128><<<dim3(gm, 1), 256, 0, stream>>>(
        Bh, Bl, Wt3h, Wt3l, bufA, N_NODES, 128, 256, as3, ad3, asv3, adv3);
    gat_aggregate_sliced<4, 32, 128, 1, false, false><<<nbs, 256, 0, stream>>>(
        bufA, asv3, adv3, row_ptr, col, b3, hout, nullptr, nullptr);

    // ---- global mean pool ----
    pool_mean4<<<dim3(G_GRAPHS, 4), 128, 0, stream>>>(hout, gstart, gout);
}

// Round 16
// 400.060 us; speedup vs baseline: 2.3527x; 2.3527x over previous
//
#include <hip/hip_runtime.h>
#include <hip/hip_bf16.h>
#include <math.h>

#define N_NODES 20000
#define N_EDGES 640000
#define ET_EDGES (N_EDGES + N_NODES)   // with self-loops
#define G_GRAPHS 64
#define NEG_SLOPE 0.2f

typedef __attribute__((ext_vector_type(8))) short s8v;   // 8 bf16 (4 VGPR)
typedef __attribute__((ext_vector_type(4))) float f4v;   // 4 fp32 acc

// fp32 -> bf16 (RNE) and back
__device__ __forceinline__ unsigned short bf_hi(float f) {
    union { float f; unsigned int u; } c; c.f = f;
    unsigned int r = (c.u + 0x7fffu + ((c.u >> 16) & 1u)) >> 16;
    return (unsigned short)r;
}
__device__ __forceinline__ float bf_f(unsigned short h) {
    union { unsigned int u; float f; } c; c.u = ((unsigned int)h) << 16;
    return c.f;
}

// ---------------- CSR construction (+ graph bounds folded in) ----------------
// NOTE (R15 lesson): do NOT fuse these into a cooperative kernel — grid.sync
// across 1024 blocks on 8 XCDs cost ~100us/barrier (build_all: 596us at
// VALUBusy 0.3%). Four small launches are 3 orders of magnitude cheaper.

__global__ void hist_dst(const int* __restrict__ ei, int* __restrict__ cnt,
                         const int* __restrict__ batch, int* __restrict__ gstart) {
    int j = blockIdx.x * blockDim.x + threadIdx.x;
    if (blockIdx.x == 0 && threadIdx.x <= G_GRAPHS) {
        int g = threadIdx.x;
        int lo = 0, hi = N_NODES;
        while (lo < hi) {              // first i with batch[i] >= g
            int mid = (lo + hi) >> 1;
            if (batch[mid] < g) lo = mid + 1; else hi = mid;
        }
        gstart[g] = lo;
    }
    if (j >= ET_EDGES) return;
    int d = (j < N_EDGES) ? ei[N_EDGES + j] : (j - N_EDGES);
    atomicAdd(&cnt[d], 1);
}

// All loads/stores staged through LDS coalesced (R14).
__global__ __launch_bounds__(1024) void scan_rowptr(const int* __restrict__ cnt,
                                                    int* __restrict__ row_ptr) {
    __shared__ int lds[N_NODES];      // 80 KB
    __shared__ int sums[1024];
    const int n = N_NODES;
    const int CH = (n + 1023) / 1024;   // 20
    int t = threadIdx.x;
    for (int i = t; i < n; i += 1024) lds[i] = cnt[i];
    __syncthreads();
    int base = t * CH;
    int s = 0;
    for (int i = 0; i < CH; ++i) {
        int idx = base + i;
        if (idx < n) s += lds[idx];
    }
    sums[t] = s;
    __syncthreads();
    for (int o = 1; o < 1024; o <<= 1) {
        int v = (t >= o) ? sums[t - o] : 0;
        __syncthreads();
        sums[t] += v;
        __syncthreads();
    }
    int run = (t == 0) ? 0 : sums[t - 1];
    for (int i = 0; i < CH; ++i) {
        int idx = base + i;
        if (idx < n) { int c = lds[idx]; lds[idx] = run; run += c; }
    }
    __syncthreads();
    for (int i = t; i < n; i += 1024) row_ptr[i] = lds[i];
    if (t == 1023) row_ptr[n] = sums[1023];
}

__global__ void fill_csr(const int* __restrict__ ei, const int* __restrict__ row_ptr,
                         int* __restrict__ cur, int* __restrict__ col) {
    int j = blockIdx.x * blockDim.x + threadIdx.x;
    if (j >= ET_EDGES) return;
    int s, d;
    if (j < N_EDGES) { s = ei[j]; d = ei[N_EDGES + j]; }
    else             { s = d = j - N_EDGES; }
    int pos = row_ptr[d] + atomicAdd(&cur[d], 1);
    col[pos] = s;
}

// ---------------- fused prep: x/W splits + buffer zeroing -------------------
// Zeroes cnt+cur, gout, and the LAYER-3 alpha accumulators only (40000 f32;
// layers 1/2 alpha is direct-stored by the 128-wide GEMM epilogue).

__global__ void prep_split(const float* __restrict__ x,
                           const float* __restrict__ W1, const float* __restrict__ W2,
                           const float* __restrict__ W3,
                           unsigned short* __restrict__ xh, unsigned short* __restrict__ xl,
                           unsigned short* __restrict__ w1h, unsigned short* __restrict__ w1l,
                           unsigned short* __restrict__ w2h, unsigned short* __restrict__ w2l,
                           unsigned short* __restrict__ w3h, unsigned short* __restrict__ w3l,
                           int* __restrict__ cntcur, float* __restrict__ gout,
                           float* __restrict__ a3z) {
    int idx = blockIdx.x * blockDim.x + threadIdx.x;
    if (idx < 640000) {                     // x: [20000*128] f32 -> hi/lo, vec4
        int i = idx * 4;
        float4 v = *(const float4*)&x[i];
        ushort4 h, l;
        h.x = bf_hi(v.x); l.x = bf_hi(v.x - bf_f(h.x));
        h.y = bf_hi(v.y); l.y = bf_hi(v.y - bf_f(h.y));
        h.z = bf_hi(v.z); l.z = bf_hi(v.z - bf_f(h.z));
        h.w = bf_hi(v.w); l.w = bf_hi(v.w - bf_f(h.w));
        *(ushort4*)&xh[i] = h;
        *(ushort4*)&xl[i] = l;
        return;
    }
    idx -= 640000;
    if (idx < 32768) {                      // W1 [128][256] -> [256][128]
        int k = idx / 256, n = idx % 256;
        float v = W1[idx];
        unsigned short h = bf_hi(v);
        w1h[n * 128 + k] = h;
        w1l[n * 128 + k] = bf_hi(v - bf_f(h));
        return;
    }
    idx -= 32768;
    if (idx < 65536) {                      // W2 [256][256] -> [256][256]
        int k = idx / 256, n = idx % 256;
        float v = W2[idx];
        unsigned short h = bf_hi(v);
        w2h[n * 256 + k] = h;
        w2l[n * 256 + k] = bf_hi(v - bf_f(h));
        return;
    }
    idx -= 65536;
    if (idx < 32768) {                      // W3 [256][128] -> [128][256]
        int k = idx / 128, n = idx % 128;
        float v = W3[idx];
        unsigned short h = bf_hi(v);
        w3h[n * 256 + k] = h;
        w3l[n * 256 + k] = bf_hi(v - bf_f(h));
        return;
    }
    idx -= 32768;
    if (idx < 10000) {                      // zero cnt+cur (40000 ints, vec4)
        *(int4*)&cntcur[idx * 4] = make_int4(0, 0, 0, 0);
        return;
    }
    idx -= 10000;
    if (idx < 2048) {                       // zero gout (8192 floats, vec4)
        *(float4*)&gout[idx * 4] = make_float4(0.f, 0.f, 0.f, 0.f);
        return;
    }
    idx -= 2048;
    if (idx < 10000) {                      // zero asv3+adv3 (40000 f32, vec4)
        *(float4*)&a3z[idx * 4] = make_float4(0.f, 0.f, 0.f, 0.f);
    }
}

// ---------------- split-bf16 MFMA GEMM, 128x128 tile + fused alpha ----------
// C = Ah*Bh + Ah*Bl + Al*Bh (lo*lo ~2^-18 rel, dropped). fp32 accumulate.
// Tile 128x128, 4 waves of 64x64 (48 MFMA per 32-K step). Register prefetch
// of the next K-tile hides HBM latency under the MFMA block (R14, -15us).
// Alpha epilogue: CPH=64 -> wave covers a full head, direct store; CPH=128
// (layer 3) -> half head, atomicAdd into pre-zeroed bufs (R10 fix).

#define LDT 40

template <int CPH>
__global__ __launch_bounds__(256) void gemm_split(
        const unsigned short* __restrict__ Ah, const unsigned short* __restrict__ Al,
        const unsigned short* __restrict__ Bh, const unsigned short* __restrict__ Bl,
        float* __restrict__ C, int M, int Nc, int K,
        const float* __restrict__ a_src, const float* __restrict__ a_dst,
        float* __restrict__ asT, float* __restrict__ adT) {
    __shared__ unsigned short lAh[128 * LDT];
    __shared__ unsigned short lAl[128 * LDT];
    __shared__ unsigned short lBh[128 * LDT];
    __shared__ unsigned short lBl[128 * LDT];
    int bm = blockIdx.x * 128, bn = blockIdx.y * 128;
    int t = threadIdx.x, w = t >> 6, lane = t & 63;
    int wm = (w >> 1) * 64, wn = (w & 1) * 64;

    f4v acc[4][4] = {};

    int sr = t >> 1, sk = (t & 1) << 4;
    int ar = bm + sr; if (ar >= M) ar = M - 1;
    const unsigned short* pAh = Ah + (size_t)ar * K + sk;
    const unsigned short* pAl = Al + (size_t)ar * K + sk;
    const unsigned short* pBh = Bh + (size_t)(bn + sr) * K + sk;
    const unsigned short* pBl = Bl + (size_t)(bn + sr) * K + sk;

    int fr = lane & 15, fk = (lane >> 4) << 3;

    // preload K-tile 0
    uint4 vh0 = *(const uint4*)(pAh + 0);
    uint4 vh1 = *(const uint4*)(pAh + 8);
    uint4 vl0 = *(const uint4*)(pAl + 0);
    uint4 vl1 = *(const uint4*)(pAl + 8);
    uint4 wh0 = *(const uint4*)(pBh + 0);
    uint4 wh1 = *(const uint4*)(pBh + 8);
    uint4 wl0 = *(const uint4*)(pBl + 0);
    uint4 wl1 = *(const uint4*)(pBl + 8);

    for (int k0 = 0; k0 < K; k0 += 32) {
        __syncthreads();
        *(uint4*)&lAh[sr * LDT + sk]     = vh0;
        *(uint4*)&lAh[sr * LDT + sk + 8] = vh1;
        *(uint4*)&lAl[sr * LDT + sk]     = vl0;
        *(uint4*)&lAl[sr * LDT + sk + 8] = vl1;
        *(uint4*)&lBh[sr * LDT + sk]     = wh0;
        *(uint4*)&lBh[sr * LDT + sk + 8] = wh1;
        *(uint4*)&lBl[sr * LDT + sk]     = wl0;
        *(uint4*)&lBl[sr * LDT + sk + 8] = wl1;
        __syncthreads();

        int kn = k0 + 32;
        if (kn < K) {                      // prefetch next tile (hides HBM)
            vh0 = *(const uint4*)(pAh + kn);
            vh1 = *(const uint4*)(pAh + kn + 8);
            vl0 = *(const uint4*)(pAl + kn);
            vl1 = *(const uint4*)(pAl + kn + 8);
            wh0 = *(const uint4*)(pBh + kn);
            wh1 = *(const uint4*)(pBh + kn + 8);
            wl0 = *(const uint4*)(pBl + kn);
            wl1 = *(const uint4*)(pBl + kn + 8);
        }

        s8v a_h[4], a_l[4], b_h[4], b_l[4];
        #pragma unroll
        for (int mi = 0; mi < 4; ++mi) {
            a_h[mi] = *(const s8v*)&lAh[(wm + mi * 16 + fr) * LDT + fk];
            a_l[mi] = *(const s8v*)&lAl[(wm + mi * 16 + fr) * LDT + fk];
        }
        #pragma unroll
        for (int nj = 0; nj < 4; ++nj) {
            b_h[nj] = *(const s8v*)&lBh[(wn + nj * 16 + fr) * LDT + fk];
            b_l[nj] = *(const s8v*)&lBl[(wn + nj * 16 + fr) * LDT + fk];
        }
        #pragma unroll
        for (int mi = 0; mi < 4; ++mi)
            #pragma unroll
            for (int nj = 0; nj < 4; ++nj) {
                acc[mi][nj] = __builtin_amdgcn_mfma_f32_16x16x32_bf16(
                    a_h[mi], b_h[nj], acc[mi][nj], 0, 0, 0);
                acc[mi][nj] = __builtin_amdgcn_mfma_f32_16x16x32_bf16(
                    a_h[mi], b_l[nj], acc[mi][nj], 0, 0, 0);
                acc[mi][nj] = __builtin_amdgcn_mfma_f32_16x16x32_bf16(
                    a_l[mi], b_h[nj], acc[mi][nj], 0, 0, 0);
            }
    }

    // C/D layout: col = lane&15, row = (lane>>4)*4 + q  [verified gfx950]
    #pragma unroll
    for (int mi = 0; mi < 4; ++mi)
        #pragma unroll
        for (int nj = 0; nj < 4; ++nj) {
            int row0 = bm + wm + mi * 16 + (lane >> 4) * 4;
            int colc = bn + wn + nj * 16 + (lane & 15);
            #pragma unroll
            for (int q = 0; q < 4; ++q) {
                int r = row0 + q;
                if (r < M) C[(size_t)r * Nc + colc] = acc[mi][nj][q];
            }
        }

    // ---- fused alpha epilogue ----
    float av_s[4], av_d[4];
    #pragma unroll
    for (int nj = 0; nj < 4; ++nj) {
        int aidx = bn + wn + nj * 16 + fr;
        av_s[nj] = a_src[aidx];
        av_d[nj] = a_dst[aidx];
    }
    int head = (bn + wn) / CPH;
    #pragma unroll
    for (int mi = 0; mi < 4; ++mi) {
        #pragma unroll
        for (int q = 0; q < 4; ++q) {
            float ps = acc[mi][0][q] * av_s[0] + acc[mi][1][q] * av_s[1]
                     + acc[mi][2][q] * av_s[2] + acc[mi][3][q] * av_s[3];
            float pd = acc[mi][0][q] * av_d[0] + acc[mi][1][q] * av_d[1]
                     + acc[mi][2][q] * av_d[2] + acc[mi][3][q] * av_d[3];
            #pragma unroll
            for (int o = 1; o < 16; o <<= 1) {
                ps += __shfl_xor(ps, o);
                pd += __shfl_xor(pd, o);
            }
            if (fr == 0) {
                int r = bm + wm + mi * 16 + (lane >> 4) * 4 + q;
                if (r < M) {
                    if (CPH == 64) {          // wave == full head: direct store
                        asT[(size_t)head * M + r] = ps;
                        adT[(size_t)head * M + r] = pd;
                    } else {                  // half head: atomic combine
                        atomicAdd(&asT[r], ps);
                        atomicAdd(&adT[r], pd);
                    }
                }
            }
        }
    }
}

// ---------------- channel-sliced softmax-aggregate (R10-measured optimum) ---
// NSLICE=4, fused softmax, fp32 table, GATHER4, VGPR 28 — every probed
// perturbation (NSLICE 1/8, unroll 8, precomputed pex, fp16 table) lost.

template <int NSLICE, int SCH, int F, int HEADS, bool DO_ELU, bool SPLIT>
__global__ __launch_bounds__(256) void gat_aggregate_sliced(
        const float* __restrict__ h,      // [N, F]
        const float* __restrict__ asT,    // [HEADS][N]
        const float* __restrict__ adT,    // [HEADS][N]
        const int* __restrict__ row_ptr,
        const int* __restrict__ col,
        const float* __restrict__ bias,   // [F]
        float* __restrict__ out,          // [N, F]   (SPLIT=false)
        unsigned short* __restrict__ oh,  // [N, F]   (SPLIT=true)
        unsigned short* __restrict__ ol) {
    constexpr int CL = SCH / 4;           // lanes per edge (16 or 8)
    constexpr int E  = 64 / CL;           // parallel edges (4 or 8)
    constexpr int CPH = F / HEADS;        // channels per head
    __shared__ int   s_off[4][64];
    __shared__ float s_p[4][64];
    int slice = blockIdx.x & (NSLICE - 1);
    int ng = blockIdx.x >> 2;             // NSLICE == 4
    int wid = threadIdx.x >> 6, lane = threadIdx.x & 63;
    int v = ng * 4 + wid;
    if (v >= N_NODES) return;
    int head = (slice * SCH) / CPH;       // layers 1/2: slice == head; layer 3: 0
    int eg = lane / CL, cl = lane % CL;
    int r0 = row_ptr[v], r1 = row_ptr[v + 1];
    float ad = adT[head * N_NODES + v];
    const float* asrc = asT + head * N_NODES;
    float acc[4] = {};
    float lsum = 0.f;
    const char* hb = (const char*)(h + slice * SCH + cl * 4);

#define GATHER4(gg)                                                        \
    {                                                                      \
        int k0 = ((gg) + 0) * E + eg;                                      \
        int k1 = ((gg) + 1) * E + eg;                                      \
        int k2 = ((gg) + 2) * E + eg;                                      \
        int k3 = ((gg) + 3) * E + eg;                                      \
        float p0 = s_p[wid][k0]; int o0 = s_off[wid][k0];                  \
        float p1 = s_p[wid][k1]; int o1 = s_off[wid][k1];                  \
        float p2 = s_p[wid][k2]; int o2 = s_off[wid][k2];                  \
        float p3 = s_p[wid][k3]; int o3 = s_off[wid][k3];                  \
        float4 h0 = *(const float4*)(hb + o0);                             \
        float4 h1 = *(const float4*)(hb + o1);                             \
        float4 h2 = *(const float4*)(hb + o2);                             \
        float4 h3 = *(const float4*)(hb + o3);                             \
        acc[0] = fmaf(p0, h0.x, acc[0]);                                   \
        acc[1] = fmaf(p0, h0.y, acc[1]);                                   \
        acc[2] = fmaf(p0, h0.z, acc[2]);                                   \
        acc[3] = fmaf(p0, h0.w, acc[3]);                                   \
        acc[0] = fmaf(p1, h1.x, acc[0]);                                   \
        acc[1] = fmaf(p1, h1.y, acc[1]);                                   \
        acc[2] = fmaf(p1, h1.z, acc[2]);                                   \
        acc[3] = fmaf(p1, h1.w, acc[3]);                                   \
        acc[0] = fmaf(p2, h2.x, acc[0]);                                   \
        acc[1] = fmaf(p2, h2.y, acc[1]);                                   \
        acc[2] = fmaf(p2, h2.z, acc[2]);                                   \
        acc[3] = fmaf(p2, h2.w, acc[3]);                                   \
        acc[0] = fmaf(p3, h3.x, acc[0]);                                   \
        acc[1] = fmaf(p3, h3.y, acc[1]);                                   \
        acc[2] = fmaf(p3, h3.z, acc[2]);                                   \
        acc[3] = fmaf(p3, h3.w, acc[3]);                                   \
    }

    for (int base = r0; base < r1; base += 64) {
        int j = base + lane;
        bool valid = j < r1;
        int s = col[valid ? j : r0];
        float e = asrc[s] + ad;
        e = (e > 0.f) ? e : NEG_SLOPE * e;
        float p = valid ? __expf(e) : 0.f;
        lsum += p;
        s_p[wid][lane] = p;
        s_off[wid][lane] = s * (F * 4);   // byte offset of row s

        int nk = min(64, r1 - base);
        int nkg = (nk + E - 1) / E;       // <= 64/E
        int g = 0;
        for (; g + 4 <= nkg; g += 4) GATHER4(g);
        if (g < nkg) GATHER4(g);          // ragged tail: extra groups have p==0
    }
#undef GATHER4

    // full-wave softmax denominator
    #pragma unroll
    for (int o = 32; o; o >>= 1) lsum += __shfl_xor(lsum, o);
    // reduce acc across edge groups (lanes differing in bits >= log2(CL))
    #pragma unroll
    for (int c = 0; c < 4; ++c) {
        #pragma unroll
        for (int o = CL; o < 64; o <<= 1) acc[c] += __shfl_xor(acc[c], o);
    }
    if (eg == 0) {
        float inv = 1.f / (lsum + 1e-16f);
        int ch0 = slice * SCH + cl * 4;
        float o4[4];
        #pragma unroll
        for (int c = 0; c < 4; ++c) {
            float o = acc[c] * inv + bias[ch0 + c];
            if (DO_ELU) o = (o > 0.f) ? o : expm1f(o);
            o4[c] = o;
        }
        if constexpr (SPLIT) {
            ushort4 hv4, lv4;
            hv4.x = bf_hi(o4[0]); lv4.x = bf_hi(o4[0] - bf_f(hv4.x));
            hv4.y = bf_hi(o4[1]); lv4.y = bf_hi(o4[1] - bf_f(hv4.y));
            hv4.z = bf_hi(o4[2]); lv4.z = bf_hi(o4[2] - bf_f(hv4.z));
            hv4.w = bf_hi(o4[3]); lv4.w = bf_hi(o4[3] - bf_f(hv4.w));
            *(ushort4*)&oh[(size_t)v * F + ch0] = hv4;
            *(ushort4*)&ol[(size_t)v * F + ch0] = lv4;
        } else {
            *(float4*)&out[(size_t)v * F + ch0] =
                make_float4(o4[0], o4[1], o4[2], o4[3]);
        }
    }
}

// ---------------- global mean pool: 4-way row-split + atomic combine --------

__global__ void pool_mean4(const float* __restrict__ hout, const int* __restrict__ gstart,
                           float* __restrict__ gout) {
    int g = blockIdx.x;       // 64
    int q = blockIdx.y;       // 4 row-quarters
    int c = threadIdx.x;      // 128 channels
    int off = gstart[g], end = gstart[g + 1];
    float inv = 1.f / fmaxf((float)(end - off), 1.0f);
    float s = 0.f;
    for (int i = off + q; i < end; i += 4) s += hout[(size_t)i * 128 + c];
    atomicAdd(&gout[g * 128 + c], s * inv);
}

// ---------------- launch ----------------

static inline size_t align_up(size_t x, size_t a) { return (x + a - 1) & ~(a - 1); }

extern "C" void kernel_launch(void* const* d_in, const int* in_sizes, int n_in,
                              void* d_out, int out_size, void* d_ws, size_t ws_size,
                              hipStream_t stream) {
    const float* x   = (const float*)d_in[0];
    const int*   ei  = (const int*)d_in[1];
    const int*   bat = (const int*)d_in[2];
    const float* W1  = (const float*)d_in[3];
    const float* as1 = (const float*)d_in[4];
    const float* ad1 = (const float*)d_in[5];
    const float* b1  = (const float*)d_in[6];
    const float* W2  = (const float*)d_in[7];
    const float* as2 = (const float*)d_in[8];
    const float* ad2 = (const float*)d_in[9];
    const float* b2  = (const float*)d_in[10];
    const float* W3  = (const float*)d_in[11];
    const float* as3 = (const float*)d_in[12];
    const float* ad3 = (const float*)d_in[13];
    const float* b3  = (const float*)d_in[14];

    float* gout = (float*)d_out;                     // [G,128]
    float* hout = (float*)d_out + G_GRAPHS * 128;    // [N,128]

    char* w = (char*)d_ws;
    size_t o = 0;
    float* bufA = (float*)(w + o);           o = align_up(o + (size_t)N_NODES * 256 * 4, 256);
    unsigned short* Bh = (unsigned short*)(w + o); o = align_up(o + (size_t)N_NODES * 256 * 2, 256);
    unsigned short* Bl = (unsigned short*)(w + o); o = align_up(o + (size_t)N_NODES * 256 * 2, 256);
    unsigned short* xh = (unsigned short*)(w + o); o = align_up(o + (size_t)N_NODES * 128 * 2, 256);
    unsigned short* xl = (unsigned short*)(w + o); o = align_up(o + (size_t)N_NODES * 128 * 2, 256);
    unsigned short* Wt1h = (unsigned short*)(w + o); o = align_up(o + (size_t)256 * 128 * 2, 256);
    unsigned short* Wt1l = (unsigned short*)(w + o); o = align_up(o + (size_t)256 * 128 * 2, 256);
    unsigned short* Wt2h = (unsigned short*)(w + o); o = align_up(o + (size_t)256 * 256 * 2, 256);
    unsigned short* Wt2l = (unsigned short*)(w + o); o = align_up(o + (size_t)256 * 256 * 2, 256);
    unsigned short* Wt3h = (unsigned short*)(w + o); o = align_up(o + (size_t)128 * 256 * 2, 256);
    unsigned short* Wt3l = (unsigned short*)(w + o); o = align_up(o + (size_t)128 * 256 * 2, 256);
    // per-layer alpha buffers (only asv3/adv3 need pre-zeroing)
    float* alpha = (float*)(w + o);
    float* asv1 = alpha;                  // [4][N]
    float* adv1 = alpha + 4 * N_NODES;    // [4][N]
    float* asv2 = alpha + 8 * N_NODES;    // [4][N]
    float* adv2 = alpha + 12 * N_NODES;   // [4][N]
    float* asv3 = alpha + 16 * N_NODES;   // [N]
    float* adv3 = alpha + 17 * N_NODES;   // [N]
    o = align_up(o + (size_t)18 * N_NODES * 4, 256);
    int* row_ptr = (int*)(w + o);  o = align_up(o + (size_t)(N_NODES + 1) * 4, 256);
    int* col     = (int*)(w + o);  o = align_up(o + (size_t)ET_EDGES * 4, 256);
    int* cnt     = (int*)(w + o);  o += (size_t)N_NODES * 4;        // cnt+cur contiguous
    int* cur     = (int*)(w + o);  o = align_up(o + (size_t)N_NODES * 4, 256);
    int* gstart  = (int*)(w + o);  o = align_up(o + (size_t)(G_GRAPHS + 1) * 4, 256);

    // ---- fused prep (splits + zeroing) + CSR build ----
    {
        int total = 640000 + 32768 + 65536 + 32768 + 10000 + 2048 + 10000;
        prep_split<<<(total + 255) / 256, 256, 0, stream>>>(
            x, W1, W2, W3, xh, xl, Wt1h, Wt1l, Wt2h, Wt2l, Wt3h, Wt3l, cnt, gout, asv3);
    }
    hist_dst<<<(ET_EDGES + 255) / 256, 256, 0, stream>>>(ei, cnt, bat, gstart);
    scan_rowptr<<<1, 1024, 0, stream>>>(cnt, row_ptr);
    fill_csr<<<(ET_EDGES + 255) / 256, 256, 0, stream>>>(ei, row_ptr, cur, col);

    int gm = (N_NODES + 127) / 128;   // 157
    int nb = (N_NODES + 3) / 4;       // 4 nodes per block
    int nbs = nb * 4;                 // x4 channel slices

    // ---- layer 1: 128 -> 4x64 (alpha fused into GEMM epilogue) ----
    gemm_split<64><<<dim3(gm, 2), 256, 0, stream>>>(
        xh, xl, Wt1h, Wt1l, bufA, N_NODES, 256, 128, as1, ad1, asv1, adv1);
    gat_aggregate_sliced<4, 64, 256, 4, true, true><<<nbs, 256, 0, stream>>>(
        bufA, asv1, adv1, row_ptr, col, b1, nullptr, Bh, Bl);

    // ---- layer 2: 256 -> 4x64 ----
    gemm_split<64><<<dim3(gm, 2), 256, 0, stream>>>(
        Bh, Bl, Wt2h, Wt2l, bufA, N_NODES, 256, 256, as2, ad2, asv2, adv2);
    gat_aggregate_sliced<4, 64, 256, 4, true, true><<<nbs, 256, 0, stream>>>(
        bufA, asv2, adv2, row_ptr, col, b2, nullptr, Bh, Bl);

    // ---- layer 3: 256 -> 128 (1 head; half-head waves -> atomics) ----
    gemm_split<128><<<dim3(gm, 1), 256, 0, stream>>>(
        Bh, Bl, Wt3h, Wt3l, bufA, N_NODES, 128, 256, as3, ad3, asv3, adv3);
    gat_aggregate_sliced<4, 32, 128, 1, false, false><<<nbs, 256, 0, stream>>>(
        bufA, asv3, adv3, row_ptr, col, b3, hout, nullptr, nullptr);

    // ---- global mean pool ----
    pool_mean4<<<dim3(G_GRAPHS, 4), 128, 0, stream>>>(hout, gstart, gout);
}